// Round 12
// baseline (602.883 us; speedup 1.0000x reference)
//
#include <hip/hip_runtime.h>

#define Bc 32
#define Kc 64
#define Wc 100
#define Hc 150
#define H3c 450
#define KWc 6400
#define ALPHAc 0.2f
#define THRESc 0.0002f

typedef unsigned int u32;
typedef unsigned short u16;
typedef __attribute__((ext_vector_type(8))) short short8;   // 8 bf16
typedef __attribute__((ext_vector_type(4))) float floatx4;  // 4 f32 acc

// ---- ws layout ----
// f32 region (float offsets):
#define OFF_WX      0u          // 204800  Wx (B,K,W) fp32
#define OFF_CS      204800u     // 2048    causesum (B,K)
#define OFF_GX      206848u     // 921600  gl proj (s,b,g)
#define OFF_HT      1128448u    // 4800    h_t (B,H)
#define OFF_Z       1133248u    // 4800    z (B,H)
#define OFF_F32_END 1138048u
// u16 region: P[kk][g=450][c=2048] bf16, c = s*32+b
#define OFF16_P     2276096u    // = OFF_F32_END*2
#define P_PER_NET   921600u     // 450*2048
#define WS_NEED_BYTES (2276096ull*2ull + 64ull*921600ull*2ull)   // 122,516,992

__device__ __forceinline__ float us2f(u16 u){ u32 x=((u32)u)<<16; return __uint_as_float(x); }
__device__ __forceinline__ u16 f2us(float f){
  u32 x = __float_as_uint(f);
  u32 r = (x + 0x7fffu + ((x>>16)&1u)) >> 16;   // RNE bf16
  return (u16)r;
}

// ---------- Wx = x @ lin_w.T + lin_b ----------
__global__ void wx_kernel(const float* __restrict__ x, const float* __restrict__ lin_w,
                          const float* __restrict__ lin_b, float* __restrict__ ws){
  int o = blockIdx.x*256 + threadIdx.x;
  if (o >= Bc*KWc) return;
  int i = o % Wc;
  int bk = o / Wc;
  const float4* xr = (const float4*)(x + bk*Wc);
  const float4* wr = (const float4*)(lin_w + i*Wc);
  float acc = lin_b[i];
  #pragma unroll
  for (int j=0;j<25;j++){
    float4 xv = xr[j], wv = wr[j];
    acc += xv.x*wv.x + xv.y*wv.y + xv.z*wv.z + xv.w*wv.w;
  }
  ws[OFF_WX + o] = acc;
}

// ---------- attention softmax + thresholded sum ----------
__global__ void attn_kernel(const float* __restrict__ y, const float* __restrict__ a,
                            const float* __restrict__ bias, float* __restrict__ ws){
  __shared__ float e_l[KWc];
  __shared__ float red[4];
  int row = blockIdx.x;          // b*64 + k
  int b = row >> 6, k = row & 63;
  int tid = threadIdx.x;
  float a0 = a[0], a1 = a[1];
  float yv = y[row];
  const float* v = ws + OFF_WX + b*KWc;
  const float* br = bias + k*KWc;
  float m = -3.4e38f;
  for (int j=tid; j<KWc; j+=256){
    float e = a0*yv + a1*v[j] + br[j];
    e = (e >= 0.f) ? e : ALPHAc*e;
    e_l[j] = e;
    m = fmaxf(m, e);
  }
  for (int o=32;o;o>>=1) m = fmaxf(m, __shfl_down(m, o));
  if ((tid&63)==0) red[tid>>6] = m;
  __syncthreads();
  m = fmaxf(fmaxf(red[0],red[1]), fmaxf(red[2],red[3]));
  __syncthreads();
  float ssum = 0.f;
  for (int j=tid; j<KWc; j+=256){
    float ex = expf(e_l[j]-m);
    e_l[j] = ex;
    ssum += ex;
  }
  for (int o=32;o;o>>=1) ssum += __shfl_down(ssum, o);
  if ((tid&63)==0) red[tid>>6] = ssum;
  __syncthreads();
  float s = red[0]+red[1]+red[2]+red[3];
  __syncthreads();
  float cs = 0.f;
  for (int j=tid; j<KWc; j+=256){
    float att = e_l[j] / s;
    if (att >= THRESc) cs += v[j];
  }
  for (int o=32;o;o>>=1) cs += __shfl_down(cs, o);
  if ((tid&63)==0) red[tid>>6] = cs;
  __syncthreads();
  if (tid==0) ws[OFF_CS + row] = red[0]+red[1]+red[2]+red[3];
}

// ---------- gl input projection ----------
__global__ void glproj_kernel(const float* __restrict__ gl_wih, const float* __restrict__ gl_bih,
                              float* __restrict__ ws){
  int o = blockIdx.x*256 + threadIdx.x;
  if (o >= Kc*Bc*H3c) return;
  int g = o % H3c;
  int t = o / H3c;               // s*32 + b
  int b = t & 31, s = t >> 5;
  float cs = ws[OFF_CS + b*Kc + s];
  const float4* xr = (const float4*)(ws + OFF_WX + b*KWc + s*Wc);
  const float4* wr = (const float4*)(gl_wih + g*Wc);
  float acc = gl_bih[g];
  #pragma unroll
  for (int j=0;j<25;j++){
    float4 wv = wr[j], xv = xr[j];
    acc += (xv.x+cs)*wv.x + (xv.y+cs)*wv.y + (xv.z+cs)*wv.z + (xv.w+cs)*wv.w;
  }
  ws[OFF_GX + o] = acc;
}

// ---------- gl recurrent GRU v5 (R8-passing): MFMA, 4 blocks x 8 batches ----------
__global__ void __launch_bounds__(512,1) glgru4_kernel(
    const float* __restrict__ gl_whh, const float* __restrict__ gl_bhh,
    float* __restrict__ ws){
  __shared__ __align__(16) u16 bF[10*16*40];
  __shared__ float g_l[480*10];
  int b0 = blockIdx.x*8;
  int tid = threadIdx.x;
  int w = tid >> 6, lane = tid & 63, quad = lane >> 4, n16 = lane & 15;

  short8 whhA[4][5];
  #pragma unroll
  for (int ti=0; ti<4; ti++){
    int tile = w*4 + ti;
    int sec = tile/10;
    int sr = (tile - sec*10)*16 + n16;
    bool rowok = (tile < 30) && (sr < Hc);
    int grow = sec*Hc + sr;
    #pragma unroll
    for (int c=0;c<5;c++){
      union { short8 v; u16 u[8]; } t8;
      #pragma unroll
      for (int j=0;j<8;j++){
        int k = c*32 + quad*8 + j;
        float v = (rowok && k < Hc) ? gl_whh[(size_t)grow*Hc + k] : 0.f;
        t8.u[j] = f2us(v);
      }
      whhA[ti][c] = t8.v;
    }
  }
  for (int i=tid; i<10*16*40/2; i+=512) ((u32*)bF)[i] = 0u;

  float hst[3] = {0.f,0.f,0.f};
  float bh_r[3], bh_z[3], bh_n[3];
  int tT[3], tBL[3];
  #pragma unroll
  for (int q=0;q<3;q++){
    int task = tid + q*512;
    if (task < 1200){
      int bl = task/150, t = task - bl*150;
      tT[q] = t; tBL[q] = bl;
      bh_r[q] = gl_bhh[t];
      bh_z[q] = gl_bhh[Hc+t];
      bh_n[q] = gl_bhh[2*Hc+t];
    } else { tT[q] = 0; tBL[q] = -1; }
  }

  for (int s=0;s<Kc;s++){
    __syncthreads();
    float gxr[3], gxz[3], gxn[3];
    const float* gxb = ws + OFF_GX + (size_t)(s*Bc)*H3c;
    #pragma unroll
    for (int q=0;q<3;q++){
      if (tBL[q] >= 0){
        const float* gp = gxb + (size_t)(b0+tBL[q])*H3c;
        int t = tT[q];
        gxr[q] = gp[t]; gxz[q] = gp[Hc+t]; gxn[q] = gp[2*Hc+t];
      }
    }
    floatx4 acc[4] = {{0.f,0.f,0.f,0.f},{0.f,0.f,0.f,0.f},{0.f,0.f,0.f,0.f},{0.f,0.f,0.f,0.f}};
    const u16* bBase = bF + (size_t)n16*40 + (size_t)quad*8;
    #pragma unroll
    for (int c=0;c<10;c++){
      short8 b8 = *(const short8*)(bBase + (size_t)c*640);
      int ca = (c<5)? c : (c-5);
      #pragma unroll
      for (int ti=0;ti<4;ti++)
        acc[ti] = __builtin_amdgcn_mfma_f32_16x16x32_bf16(whhA[ti][ca], b8, acc[ti], 0,0,0);
    }
    if (n16 < 8){
      #pragma unroll
      for (int ti=0;ti<4;ti++){
        int tile = w*4 + ti;
        if (tile < 30){
          int row0 = tile*16 + quad*4;
          float* gp = g_l + row0*10 + n16;
          #pragma unroll
          for (int r=0;r<4;r++) gp[r*10] = acc[ti][r];
        }
      }
    }
    __syncthreads();
    #pragma unroll
    for (int q=0;q<3;q++){
      if (tBL[q] >= 0){
        int t = tT[q], bl = tBL[q];
        float a_r = gxr[q] + g_l[t*10+bl] + bh_r[q];
        float a_z = gxz[q] + g_l[(160+t)*10+bl] + bh_z[q];
        float r  = 1.f/(1.f+__expf(-a_r));
        float zz = 1.f/(1.f+__expf(-a_z));
        float nx = gxn[q] + r*(g_l[(320+t)*10+bl] + bh_n[q]);
        nx = fminf(fmaxf(nx,-15.f),15.f);
        float e2 = __expf(2.f*nx);
        float n = (e2-1.f)/(e2+1.f);
        float h = (1.f-zz)*n + zz*hst[q];
        hst[q] = h;
        u16 hi = f2us(h); float hif = us2f(hi); u16 lo = f2us(h - hif);
        bF[(t>>5)*640 + bl*40 + (t&31)] = hi;
        bF[(5+(t>>5))*640 + bl*40 + (t&31)] = lo;
      }
    }
  }
  #pragma unroll
  for (int q=0;q<3;q++){
    if (tBL[q] >= 0)
      ws[OFF_HT + (size_t)(b0+tBL[q])*Hc + tT[q]] = hst[q];
  }
}

// ---------- z = mu + sigma * z_noise ----------
__global__ void z_kernel(const float* __restrict__ z_noise, const float* __restrict__ mu_w,
                         const float* __restrict__ mu_b, const float* __restrict__ std_w,
                         const float* __restrict__ std_b, float* __restrict__ ws){
  int o = blockIdx.x*256 + threadIdx.x;
  if (o >= Bc*Hc) return;
  int t = o % Hc, b = o / Hc;
  const float* h = ws + OFF_HT + b*Hc;
  const float2* mwr = (const float2*)(mu_w + t*Hc);
  const float2* swr = (const float2*)(std_w + t*Hc);
  float mu = mu_b[t], lv = std_b[t];
  for (int j=0;j<Hc/2;j++){
    float2 mw = mwr[j], sw = swr[j];
    float h0 = h[2*j], h1 = h[2*j+1];
    mu += h0*mw.x + h1*mw.y;
    lv += h0*sw.x + h1*sw.y;
  }
  float sg = expf(0.5f*lv);
  ws[OFF_Z + o] = mu + sg*z_noise[o];
}

// ---------- ihproj: P[kk][g][c] = bih[g] + Wih_kk[g,:]·x[c], bf16; c = s*32+b ----------
// grid 256 = (cq 0..3)*64 + kk; block does c-tiles cq*32 .. cq*32+31 (16 cols each).
__global__ void __launch_bounds__(640,3) ihproj_kernel(
    const float* __restrict__ net_wih, const float* __restrict__ net_bih,
    const float* __restrict__ ws, u16* __restrict__ p16){
  __shared__ __align__(16) u16 bX[4*16*40];   // [chunk][n=16][k stride 40]
  int kk = blockIdx.x & 63, cq = blockIdx.x >> 6;
  int tid = threadIdx.x;
  int w = tid >> 6, lane = tid & 63, quad = lane >> 4, n16 = lane & 15;
  const float* wihk = net_wih + (size_t)kk*H3c*Wc;
  const float* bihk = net_bih + kk*H3c;

  // A-frags (wih), rows sr = w*16+n16 per section
  int sr = w*16 + n16;
  bool rok = sr < Hc;
  short8 Ai[3][4];
  #pragma unroll
  for (int sec=0;sec<3;sec++){
    int grow = sec*Hc + sr;
    #pragma unroll
    for (int c=0;c<4;c++){
      union { short8 v; u16 u[8]; } t8;
      #pragma unroll
      for (int j=0;j<8;j++){
        int k = c*32 + quad*8 + j;
        t8.u[j] = f2us((rok && k < Wc) ? wihk[(size_t)grow*Wc + k] : 0.f);
      }
      Ai[sec][c] = t8.v;
    }
  }
  // bias per lane C-row
  int t0 = w*16 + quad*4;
  float bI[3][4];
  #pragma unroll
  for (int sec=0;sec<3;sec++)
    #pragma unroll
    for (int r=0;r<4;r++){
      int t = t0 + r;
      bI[sec][r] = (t < Hc) ? bihk[sec*Hc + t] : 0.f;
    }

  for (int i=tid; i<4*16*40/2; i+=640) ((u32*)bX)[i] = 0u;   // k-pads stay zero

  u16* Pk = p16 + (size_t)kk*P_PER_NET;
  for (int ct = cq*32; ct < cq*32+32; ct++){
    __syncthreads();   // previous tile's reads done
    for (int it=tid; it<1600; it+=640){
      int n = it/100, i = it - (it/100)*100;
      int c = ct*16 + n, s = c >> 5, b = c & 31;
      bX[(i>>5)*640 + n*40 + (i&31)] = f2us(ws[OFF_WX + (size_t)b*KWc + s*Wc + i]);
    }
    __syncthreads();
    floatx4 acc0 = {bI[0][0],bI[0][1],bI[0][2],bI[0][3]};
    floatx4 acc1 = {bI[1][0],bI[1][1],bI[1][2],bI[1][3]};
    floatx4 acc2 = {bI[2][0],bI[2][1],bI[2][2],bI[2][3]};
    const u16* base = bX + (size_t)n16*40 + (size_t)quad*8;
    #pragma unroll
    for (int c=0;c<4;c++){
      short8 b8 = *(const short8*)(base + (size_t)c*640);
      acc0 = __builtin_amdgcn_mfma_f32_16x16x32_bf16(Ai[0][c], b8, acc0, 0,0,0);
      acc1 = __builtin_amdgcn_mfma_f32_16x16x32_bf16(Ai[1][c], b8, acc1, 0,0,0);
      acc2 = __builtin_amdgcn_mfma_f32_16x16x32_bf16(Ai[2][c], b8, acc2, 0,0,0);
    }
    // C: col=n16, row=quad*4+r
    #pragma unroll
    for (int r=0;r<4;r++){
      int t = t0 + r;
      if (t < Hc){
        size_t col = (size_t)ct*16 + n16;
        Pk[((size_t)(0*Hc+t))*2048 + col] = f2us(acc0[r]);
        Pk[((size_t)(1*Hc+t))*2048 + col] = f2us(acc1[r]);
        Pk[((size_t)(2*Hc+t))*2048 + col] = f2us(acc2[r]);
      }
    }
  }
}

// ---------- causes v7: hh-only MFMA (P precomputed), no spill, one barrier/step ----------
__global__ void __launch_bounds__(640,3) causes5_kernel(
    const float* __restrict__ net_whh, const float* __restrict__ net_bhh,
    const float* __restrict__ ws, const u16* __restrict__ p16, float* __restrict__ out){
  __shared__ __align__(16) u16 bF[2][10*16*40];   // ping-pong h panels
  int kk = blockIdx.x & 63, bg = blockIdx.x >> 6, b0 = bg*8;
  int tid = threadIdx.x;
  int w = tid >> 6, lane = tid & 63, quad = lane >> 4, n16 = lane & 15;
  const float* whhk = net_whh + (size_t)kk*H3c*Hc;
  const float* bhhk = net_bhh + kk*H3c;

  int sr = w*16 + n16;
  bool rok = sr < Hc;
  short8 Ah[3][5];
  #pragma unroll
  for (int sec=0;sec<3;sec++){
    int grow = sec*Hc + sr;
    #pragma unroll
    for (int c=0;c<5;c++){
      union { short8 v; u16 u[8]; } t8;
      #pragma unroll
      for (int j=0;j<8;j++){
        int k = c*32 + quad*8 + j;
        t8.u[j] = f2us((rok && k < Hc) ? whhk[(size_t)grow*Hc + k] : 0.f);
      }
      Ah[sec][c] = t8.v;
    }
  }

  int t0 = w*16 + quad*4;
  float bR[4], bZ[4], bN[4], hst[4];
  #pragma unroll
  for (int r=0;r<4;r++){
    int t = t0 + r;
    bool v = (t < Hc) && (n16 < 8);
    bR[r] = v ? bhhk[t] : 0.f;
    bZ[r] = v ? bhhk[Hc+t] : 0.f;
    bN[r] = v ? bhhk[2*Hc+t] : 0.f;
    hst[r] = v ? ws[OFF_Z + (size_t)(b0+n16)*Hc + t] : 0.f;
  }

  for (int i=tid; i<2*10*16*40/2; i+=640) ((u32*)bF)[i] = 0u;
  __syncthreads();
  if (n16 < 8){
    #pragma unroll
    for (int p=0;p<2;p++){
      int t = t0 + p*2;
      u16 h0 = f2us(hst[p*2]);   u16 l0 = f2us(hst[p*2]   - us2f(h0));
      u16 h1 = f2us(hst[p*2+1]); u16 l1 = f2us(hst[p*2+1] - us2f(h1));
      *(u32*)&bF[0][(t>>5)*640     + n16*40 + (t&31)] = (u32)h0 | ((u32)h1<<16);
      *(u32*)&bF[0][(5+(t>>5))*640 + n16*40 + (t&31)] = (u32)l0 | ((u32)l1<<16);
    }
  }

  const u16* Pk = p16 + (size_t)kk*P_PER_NET;
  for (int s=0;s<Kc;s++){
    __syncthreads();
    const u16* rb = bF[s&1];
    u16* wb = bF[(s+1)&1];
    // P prefetch (coalesced in bb; overlaps MFMA)
    float pr[4], pz[4], pn[4];
    #pragma unroll
    for (int r=0;r<4;r++){
      int t = t0 + r;
      bool v = (t < Hc) && (n16 < 8);
      if (v){
        size_t col = (size_t)s*32 + b0 + n16;
        pr[r] = us2f(Pk[((size_t)t)*2048 + col]);
        pz[r] = us2f(Pk[((size_t)(Hc+t))*2048 + col]);
        pn[r] = us2f(Pk[((size_t)(2*Hc+t))*2048 + col]);
      } else { pr[r]=pz[r]=pn[r]=0.f; }
    }
    floatx4 aR = {bR[0],bR[1],bR[2],bR[3]};
    floatx4 aZ = {bZ[0],bZ[1],bZ[2],bZ[3]};
    floatx4 aN = {bN[0],bN[1],bN[2],bN[3]};
    const u16* base = rb + (size_t)n16*40 + (size_t)quad*8;
    #pragma unroll
    for (int c=0;c<10;c++){
      short8 b8 = *(const short8*)(base + (size_t)c*640);
      int ca = (c<5)? c : (c-5);
      aR = __builtin_amdgcn_mfma_f32_16x16x32_bf16(Ah[0][ca], b8, aR, 0,0,0);
      aZ = __builtin_amdgcn_mfma_f32_16x16x32_bf16(Ah[1][ca], b8, aZ, 0,0,0);
      aN = __builtin_amdgcn_mfma_f32_16x16x32_bf16(Ah[2][ca], b8, aN, 0,0,0);
    }
    #pragma unroll
    for (int r=0;r<4;r++){
      bool v = (t0 + r < Hc) && (n16 < 8);
      float rr = 1.f/(1.f+__expf(-(aR[r] + pr[r])));
      float zz = 1.f/(1.f+__expf(-(aZ[r] + pz[r])));
      float nx = pn[r] + rr*aN[r];
      nx = fminf(fmaxf(nx,-15.f),15.f);
      float e2 = __expf(2.f*nx);
      float n = (e2-1.f)/(e2+1.f);
      float h = (1.f-zz)*n + zz*hst[r];
      hst[r] = v ? h : 0.f;
    }
    if (n16 < 8){
      #pragma unroll
      for (int p=0;p<2;p++){
        int t = t0 + p*2;
        u16 h0 = f2us(hst[p*2]);   u16 l0 = f2us(hst[p*2]   - us2f(h0));
        u16 h1 = f2us(hst[p*2+1]); u16 l1 = f2us(hst[p*2+1] - us2f(h1));
        *(u32*)&wb[(t>>5)*640     + n16*40 + (t&31)] = (u32)h0 | ((u32)h1<<16);
        *(u32*)&wb[(5+(t>>5))*640 + n16*40 + (t&31)] = (u32)l0 | ((u32)l1<<16);
      }
    }
  }
  if (n16 < 8){
    #pragma unroll
    for (int r=0;r<4;r++){
      int t = t0 + r;
      if (t < Hc)
        out[((size_t)(b0+n16)*Kc + kk)*Hc + t] = hst[r];
    }
  }
}

// ---------- causes v6 fallback (R11-passing, used when ws too small) ----------
__global__ void __launch_bounds__(640,3) causes4_kernel(
    const float* __restrict__ net_wih, const float* __restrict__ net_whh,
    const float* __restrict__ net_bih, const float* __restrict__ net_bhh,
    const float* __restrict__ ws, float* __restrict__ out){
  __shared__ __align__(16) u16 bF[2][14*16*40];
  int kk = blockIdx.x & 63, bg = blockIdx.x >> 6, b0 = bg*8;
  int tid = threadIdx.x;
  int w = tid >> 6, lane = tid & 63, quad = lane >> 4, n16 = lane & 15;
  const float* whhk = net_whh + (size_t)kk*H3c*Hc;
  const float* wihk = net_wih + (size_t)kk*H3c*Wc;
  const float* bihk = net_bih + kk*H3c;
  const float* bhhk = net_bhh + kk*H3c;

  int sr = w*16 + n16;
  bool rok = sr < Hc;
  short8 Ah[3][5], Ai[3][4];
  #pragma unroll
  for (int sec=0;sec<3;sec++){
    int grow = sec*Hc + sr;
    #pragma unroll
    for (int c=0;c<5;c++){
      union { short8 v; u16 u[8]; } t8;
      #pragma unroll
      for (int j=0;j<8;j++){
        int k = c*32 + quad*8 + j;
        t8.u[j] = f2us((rok && k < Hc) ? whhk[(size_t)grow*Hc + k] : 0.f);
      }
      Ah[sec][c] = t8.v;
    }
    #pragma unroll
    for (int c=0;c<4;c++){
      union { short8 v; u16 u[8]; } t8;
      #pragma unroll
      for (int j=0;j<8;j++){
        int k = c*32 + quad*8 + j;
        t8.u[j] = f2us((rok && k < Wc) ? wihk[(size_t)grow*Wc + k] : 0.f);
      }
      Ai[sec][c] = t8.v;
    }
  }

  int t0 = w*16 + quad*4;
  float bR[4], bZ[4], bNh[4], bNp[4], hst[4];
  #pragma unroll
  for (int r=0;r<4;r++){
    int t = t0 + r;
    bool v = (t < Hc) && (n16 < 8);
    bR[r]  = v ? (bhhk[t] + bihk[t]) : 0.f;
    bZ[r]  = v ? (bhhk[Hc+t] + bihk[Hc+t]) : 0.f;
    bNh[r] = v ? bhhk[2*Hc+t] : 0.f;
    bNp[r] = v ? bihk[2*Hc+t] : 0.f;
    hst[r] = v ? ws[OFF_Z + (size_t)(b0+n16)*Hc + t] : 0.f;
  }

  for (int i=tid; i<2*14*16*40/2; i+=640) ((u32*)bF)[i] = 0u;
  __syncthreads();
  if (n16 < 8){
    #pragma unroll
    for (int p=0;p<2;p++){
      int t = t0 + p*2;
      u16 h0 = f2us(hst[p*2]);   u16 l0 = f2us(hst[p*2]   - us2f(h0));
      u16 h1 = f2us(hst[p*2+1]); u16 l1 = f2us(hst[p*2+1] - us2f(h1));
      *(u32*)&bF[0][(t>>5)*640     + n16*40 + (t&31)] = (u32)h0 | ((u32)h1<<16);
      *(u32*)&bF[0][(5+(t>>5))*640 + n16*40 + (t&31)] = (u32)l0 | ((u32)l1<<16);
    }
  }
  for (int it=tid; it<800; it+=640){
    int bb = it/100, i = it - bb*100;
    bF[0][(10+(i>>5))*640 + bb*40 + (i&31)] = f2us(ws[OFF_WX + (size_t)(b0+bb)*KWc + i]);
  }

  for (int s=0;s<Kc;s++){
    __syncthreads();
    const u16* rb = bF[s&1];
    u16* wb = bF[(s+1)&1];
    if (s < Kc-1){
      for (int it=tid; it<800; it+=640){
        int bb = it/100, i = it - bb*100;
        wb[(10+(i>>5))*640 + bb*40 + (i&31)] = f2us(ws[OFF_WX + (size_t)(b0+bb)*KWc + (s+1)*Wc + i]);
      }
    }
    floatx4 aR  = {bR[0],bR[1],bR[2],bR[3]};
    floatx4 aZ  = {bZ[0],bZ[1],bZ[2],bZ[3]};
    floatx4 aNh = {bNh[0],bNh[1],bNh[2],bNh[3]};
    floatx4 aNp = {bNp[0],bNp[1],bNp[2],bNp[3]};
    const u16* base = rb + (size_t)n16*40 + (size_t)quad*8;
    #pragma unroll
    for (int c=0;c<14;c++){
      short8 b8 = *(const short8*)(base + (size_t)c*640);
      if (c < 10){
        int ca = (c<5)? c : (c-5);
        aR  = __builtin_amdgcn_mfma_f32_16x16x32_bf16(Ah[0][ca], b8, aR, 0,0,0);
        aZ  = __builtin_amdgcn_mfma_f32_16x16x32_bf16(Ah[1][ca], b8, aZ, 0,0,0);
        aNh = __builtin_amdgcn_mfma_f32_16x16x32_bf16(Ah[2][ca], b8, aNh,0,0,0);
      } else {
        int ca = c-10;
        aR  = __builtin_amdgcn_mfma_f32_16x16x32_bf16(Ai[0][ca], b8, aR, 0,0,0);
        aZ  = __builtin_amdgcn_mfma_f32_16x16x32_bf16(Ai[1][ca], b8, aZ, 0,0,0);
        aNp = __builtin_amdgcn_mfma_f32_16x16x32_bf16(Ai[2][ca], b8, aNp,0,0,0);
      }
    }
    #pragma unroll
    for (int r=0;r<4;r++){
      bool v = (t0 + r < Hc) && (n16 < 8);
      float rr = 1.f/(1.f+__expf(-aR[r]));
      float zz = 1.f/(1.f+__expf(-aZ[r]));
      float nx = aNp[r] + rr*aNh[r];
      nx = fminf(fmaxf(nx,-15.f),15.f);
      float e2 = __expf(2.f*nx);
      float n = (e2-1.f)/(e2+1.f);
      float h = (1.f-zz)*n + zz*hst[r];
      hst[r] = v ? h : 0.f;
    }
    if (n16 < 8){
      #pragma unroll
      for (int p=0;p<2;p++){
        int t = t0 + p*2;
        u16 h0 = f2us(hst[p*2]);   u16 l0 = f2us(hst[p*2]   - us2f(h0));
        u16 h1 = f2us(hst[p*2+1]); u16 l1 = f2us(hst[p*2+1] - us2f(h1));
        *(u32*)&wb[(t>>5)*640     + n16*40 + (t&31)] = (u32)h0 | ((u32)h1<<16);
        *(u32*)&wb[(5+(t>>5))*640 + n16*40 + (t&31)] = (u32)l0 | ((u32)l1<<16);
      }
    }
  }
  if (n16 < 8){
    #pragma unroll
    for (int r=0;r<4;r++){
      int t = t0 + r;
      if (t < Hc)
        out[((size_t)(b0+n16)*Kc + kk)*Hc + t] = hst[r];
    }
  }
}

extern "C" void kernel_launch(void* const* d_in, const int* in_sizes, int n_in,
                              void* d_out, int out_size, void* d_ws, size_t ws_size,
                              hipStream_t stream){
  const float* x        = (const float*)d_in[0];
  const float* y        = (const float*)d_in[1];
  const float* z_noise  = (const float*)d_in[2];
  const float* lin_w    = (const float*)d_in[3];
  const float* lin_b    = (const float*)d_in[4];
  const float* a        = (const float*)d_in[5];
  const float* bias     = (const float*)d_in[6];
  const float* gl_wih   = (const float*)d_in[7];
  const float* gl_whh   = (const float*)d_in[8];
  const float* gl_bih   = (const float*)d_in[9];
  const float* gl_bhh   = (const float*)d_in[10];
  const float* mu_w     = (const float*)d_in[11];
  const float* mu_b     = (const float*)d_in[12];
  const float* std_w    = (const float*)d_in[13];
  const float* std_b    = (const float*)d_in[14];
  const float* net_wih  = (const float*)d_in[15];
  const float* net_whh  = (const float*)d_in[16];
  const float* net_bih  = (const float*)d_in[17];
  const float* net_bhh  = (const float*)d_in[18];
  float* ws = (float*)d_ws;
  float* out = (float*)d_out;
  bool big = ws_size >= (size_t)WS_NEED_BYTES;

  wx_kernel<<<(Bc*KWc+255)/256, 256, 0, stream>>>(x, lin_w, lin_b, ws);
  attn_kernel<<<Bc*Kc, 256, 0, stream>>>(y, a, bias, ws);
  glproj_kernel<<<(Kc*Bc*H3c+255)/256, 256, 0, stream>>>(gl_wih, gl_bih, ws);
  if (big)
    ihproj_kernel<<<256, 640, 0, stream>>>(net_wih, net_bih, ws, (u16*)d_ws + OFF16_P);
  glgru4_kernel<<<4, 512, 0, stream>>>(gl_whh, gl_bhh, ws);
  z_kernel<<<(Bc*Hc+255)/256, 256, 0, stream>>>(z_noise, mu_w, mu_b, std_w, std_b, ws);
  if (big)
    causes5_kernel<<<Kc*4, 640, 0, stream>>>(net_whh, net_bhh, ws, (const u16*)d_ws + OFF16_P, out);
  else
    causes4_kernel<<<Kc*4, 640, 0, stream>>>(net_wih, net_whh, net_bih, net_bhh, ws, out);
}